// Round 1
// baseline (4470.207 us; speedup 1.0000x reference)
//
#include <hip/hip_runtime.h>

// Sparse BasicBlock (SBNet-style), fp32 correctness-first baseline.
//   u   = mask * vector * relu(bn1(conv1(x * mask_dilate)))
//   out = relu(x + mask * bn2(conv2(u)))
// (mask is binary and mask_dilate>=mask pointwise, so all later mask products
//  collapse onto a single mask factor; bn of a masked value equals bn of the
//  raw value wherever mask==1, and the final mask multiply kills mask==0.)

#define EPS 1e-5f

constexpr int B = 32, C = 256, H = 56, W = 56;
constexpr int CO_TILE = 128;       // output channels per block
constexpr int TH = 8, TW = 8;      // spatial tile (56 = 7*8, exact)
constexpr int CI_CHUNK = 8;        // input channels staged per LDS round
constexpr int IN_H = TH + 2;       // 10 (halo)
constexpr int IN_W = TW + 2;       // 10
constexpr int IN_WP = 12;          // padded row (keeps 8B align for float2 reads)

// ---- weight pre-transpose: w[co][ci][k] -> wt[ci][k][co] (coalesced staging) ----
__global__ void transpose_weights(const float* __restrict__ w1,
                                  const float* __restrict__ w2,
                                  float* __restrict__ w1t,
                                  float* __restrict__ w2t) {
    int id = blockIdx.x * 256 + threadIdx.x;
    const int total = C * C * 9;
    if (id >= total) return;
    int co = id & 255;            // fastest
    int k  = (id >> 8) % 9;
    int ci = id / (256 * 9);
    w1t[id] = w1[(co * C + ci) * 9 + k];
    w2t[id] = w2[(co * C + ci) * 9 + k];
}

template <bool IS_CONV1>
__global__ __launch_bounds__(256, 3)
void conv_bn_kernel(const float* __restrict__ src,   // x (conv1) or u (conv2)
                    const float* __restrict__ wtt,   // transposed weights [ci][k][co]
                    const float* __restrict__ mask,  // [B,1,H,W]
                    const float* __restrict__ md,    // mask_dilate (conv1 only)
                    const float* __restrict__ vec,   // vector [B,C] (conv1 only)
                    const float* __restrict__ bng,
                    const float* __restrict__ bnb,
                    const float* __restrict__ bnm,
                    const float* __restrict__ bnv,
                    const float* __restrict__ ident, // x (conv2 only)
                    float* __restrict__ dst) {
    __shared__ __align__(16) float s_in[CI_CHUNK][IN_H][IN_WP];
    __shared__ __align__(16) float s_wt[CI_CHUNK][9][CO_TILE];

    const int tid = threadIdx.x;
    const int bx = blockIdx.x;              // 0..48
    const int ty = bx / 7, tx = bx - ty * 7;
    const int y0 = ty * TH, x0 = tx * TW;
    const int co0 = blockIdx.y * CO_TILE;
    const int n = blockIdx.z;

    const int cg = tid >> 3;                // 0..31 -> 4-channel group
    const int prow = tid & 7;               // 0..7  -> full 8-wide output row
    const int cobase = cg * 4;

    float acc[4][8];
    #pragma unroll
    for (int j = 0; j < 4; ++j)
        #pragma unroll
        for (int p = 0; p < 8; ++p) acc[j][p] = 0.f;

    const float* srcn = src + (size_t)n * C * H * W;
    const float* mdn = IS_CONV1 ? (md + (size_t)n * H * W) : nullptr;

    for (int ci0 = 0; ci0 < C; ci0 += CI_CHUNK) {
        __syncthreads();   // protect LDS from previous iteration's readers
        // ---- stage input tile (halo, zero-padded, mask_dilate fused for conv1) ----
        #pragma unroll
        for (int i = 0; i < 4; ++i) {
            int e = tid + i * 256;
            if (e < CI_CHUNK * IN_H * IN_W) {
                int ci  = e / (IN_H * IN_W);
                int rem = e - ci * (IN_H * IN_W);
                int iy  = rem / IN_W;
                int ix  = rem - iy * IN_W;
                int gy = y0 + iy - 1, gx = x0 + ix - 1;
                float v = 0.f;
                if ((unsigned)gy < (unsigned)H && (unsigned)gx < (unsigned)W) {
                    v = srcn[(size_t)(ci0 + ci) * (H * W) + gy * W + gx];
                    if (IS_CONV1) v *= mdn[gy * W + gx];
                }
                s_in[ci][iy][ix] = v;
            }
        }
        // ---- stage weights: s_wt[ci][k][co] <- wtt (coalesced: co contiguous) ----
        {
            const float* wsrc = wtt + (size_t)ci0 * (9 * C) + co0;
            float* s_wt_flat = &s_wt[0][0][0];
            #pragma unroll
            for (int i = 0; i < 36; ++i) {
                int e = tid + i * 256;              // 8*9*128 = 9216 = 36*256 exact
                int ci  = e / (9 * CO_TILE);
                int rem = e - ci * (9 * CO_TILE);
                int k  = rem >> 7;                  // /128
                int co = rem & 127;
                s_wt_flat[e] = wsrc[ci * (9 * C) + k * C + co];
            }
        }
        __syncthreads();

        // ---- compute: 4 co x 8 px per thread ----
        for (int ci = 0; ci < CI_CHUNK; ++ci) {
            #pragma unroll
            for (int kh = 0; kh < 3; ++kh) {
                float xr[10];
                #pragma unroll
                for (int i = 0; i < 5; ++i) {       // ds_read_b64 x5 per row
                    float2 t = *(const float2*)&s_in[ci][prow + kh][2 * i];
                    xr[2 * i] = t.x; xr[2 * i + 1] = t.y;
                }
                #pragma unroll
                for (int kw = 0; kw < 3; ++kw) {
                    float4 wk = *(const float4*)&s_wt[ci][kh * 3 + kw][cobase];
                    #pragma unroll
                    for (int px = 0; px < 8; ++px) {
                        float iv = xr[px + kw];
                        acc[0][px] = fmaf(wk.x, iv, acc[0][px]);
                        acc[1][px] = fmaf(wk.y, iv, acc[1][px]);
                        acc[2][px] = fmaf(wk.z, iv, acc[2][px]);
                        acc[3][px] = fmaf(wk.w, iv, acc[3][px]);
                    }
                }
            }
        }
    }

    // ---- epilogue ----
    const int oy = y0 + prow;
    const size_t mrow = ((size_t)n * H + oy) * W + x0;
    const float4 mk0 = *(const float4*)&mask[mrow];
    const float4 mk1 = *(const float4*)&mask[mrow + 4];
    const float mk[8] = {mk0.x, mk0.y, mk0.z, mk0.w, mk1.x, mk1.y, mk1.z, mk1.w};

    #pragma unroll
    for (int j = 0; j < 4; ++j) {
        const int co = co0 + cobase + j;
        const float inv  = rsqrtf(bnv[co] + EPS) * bng[co];
        const float beta = bnb[co] - bnm[co] * inv;
        const size_t obase = ((size_t)(n * C + co) * H + oy) * W + x0;
        float o[8];
        if (IS_CONV1) {
            const float s = vec[n * C + co];
            #pragma unroll
            for (int p = 0; p < 8; ++p)
                o[p] = fmaxf(acc[j][p] * inv + beta, 0.f) * mk[p] * s;
        } else {
            const float4 xv0 = *(const float4*)&ident[obase];
            const float4 xv1 = *(const float4*)&ident[obase + 4];
            const float xv[8] = {xv0.x, xv0.y, xv0.z, xv0.w, xv1.x, xv1.y, xv1.z, xv1.w};
            #pragma unroll
            for (int p = 0; p < 8; ++p)
                o[p] = fmaxf(xv[p] + mk[p] * (acc[j][p] * inv + beta), 0.f);
        }
        *(float4*)&dst[obase]     = make_float4(o[0], o[1], o[2], o[3]);
        *(float4*)&dst[obase + 4] = make_float4(o[4], o[5], o[6], o[7]);
    }
}

extern "C" void kernel_launch(void* const* d_in, const int* in_sizes, int n_in,
                              void* d_out, int out_size, void* d_ws, size_t ws_size,
                              hipStream_t stream) {
    const float* x    = (const float*)d_in[0];
    const float* mask = (const float*)d_in[1];
    const float* md   = (const float*)d_in[2];
    const float* vec  = (const float*)d_in[3];
    const float* w1   = (const float*)d_in[4];
    const float* bn1g = (const float*)d_in[5];
    const float* bn1b = (const float*)d_in[6];
    const float* bn1m = (const float*)d_in[7];
    const float* bn1v = (const float*)d_in[8];
    const float* w2   = (const float*)d_in[9];
    const float* bn2g = (const float*)d_in[10];
    const float* bn2b = (const float*)d_in[11];
    const float* bn2m = (const float*)d_in[12];
    const float* bn2v = (const float*)d_in[13];
    float* out = (float*)d_out;

    // workspace layout: u (fp32 intermediate) | w1t | w2t
    float* u = (float*)d_ws;
    const size_t uelems = (size_t)B * C * H * W;
    float* w1t = u + uelems;
    float* w2t = w1t + (size_t)C * C * 9;

    transpose_weights<<<dim3((C * C * 9 + 255) / 256), dim3(256), 0, stream>>>(
        w1, w2, w1t, w2t);

    dim3 grid(49, C / CO_TILE, B);
    conv_bn_kernel<true><<<grid, dim3(256), 0, stream>>>(
        x, w1t, mask, md, vec, bn1g, bn1b, bn1m, bn1v, nullptr, u);
    conv_bn_kernel<false><<<grid, dim3(256), 0, stream>>>(
        u, w2t, mask, nullptr, nullptr, bn2g, bn2b, bn2m, bn2v, x, out);
}

// Round 2
// 536.007 us; speedup vs baseline: 8.3398x; 8.3398x over previous
//
#include <hip/hip_runtime.h>
#include <cstdint>

// Sparse BasicBlock via bf16 MFMA implicit GEMM (32x32x16).
//   u   = mask * vector * relu(bn1(conv1(x * mask_dilate)))   [NHWC bf16]
//   out = relu(x + mask * bn2(conv2(u)))                      [NCHW f32]
// conv1: A=pixels(M=256px band 4y*64x), B=weights(N=128co) -> D col=co (NHWC store)
// conv2: A=weights(M=128co), B=pixels(N=256px)            -> D col=px (NCHW store)
// LDS frags: s_in[half][6y][66x][8ci], s_w[tap][half][128co][8ci] (contiguous-K b128)

#define EPS 1e-5f

constexpr int Bn = 32, Cc = 256, Hh = 56, Ww = 56;
constexpr int HW = Hh * Ww;                 // 3136
constexpr int WP_ELEMS = 2 * 16 * 9 * 2 * 128 * 8;   // 589824 per conv

typedef __bf16 bf16x8 __attribute__((ext_vector_type(8)));
typedef float  f32x16 __attribute__((ext_vector_type(16)));

// ---- pack x*mask_dilate -> NHWC bf16 ----
__global__ void pack_xm(const float* __restrict__ x, const float* __restrict__ md,
                        __bf16* __restrict__ xm) {
    int blk = blockIdx.x, tid = threadIdx.x;
    int p = tid & 31, cg = tid >> 5;
    int px0 = blk * 32;
    int img = blk / 98;
    int s = (blk - img * 98) * 32 + p;           // pixel within image
    float mdv = md[px0 + p];
    #pragma unroll
    for (int it = 0; it < 4; ++it) {
        int c = cg * 8 + it * 64;
        bf16x8 v;
        #pragma unroll
        for (int j = 0; j < 8; ++j)
            v[j] = (__bf16)(x[(size_t)(img * Cc + c + j) * HW + s] * mdv);
        *(bf16x8*)&xm[(size_t)(px0 + p) * Cc + c] = v;
    }
}

// ---- pack weights: w[co][ci][tap] f32 -> wp[coblk][chunk][tap][half][co128][8ci] bf16 ----
__global__ void pack_w(const float* __restrict__ w1, const float* __restrict__ w2,
                       __bf16* __restrict__ wp1, __bf16* __restrict__ wp2) {
    int id = blockIdx.x * 256 + threadIdx.x;     // < 589824
    const float* w = blockIdx.y ? w2 : w1;
    __bf16* wp = blockIdx.y ? wp2 : wp1;
    int j = id & 7; int t = id >> 3;
    int col = t & 127; t >>= 7;
    int half = t & 1; t >>= 1;
    int tap = t % 9; t /= 9;
    int chunk = t & 15; int coblk = t >> 4;
    int co = coblk * 128 + col;
    int ci = chunk * 16 + half * 8 + j;
    wp[id] = (__bf16)(w[((size_t)co * Cc + ci) * 9 + tap]);
}

// ---- fold BN params ----
__global__ void bn_prep(const float* g1, const float* b1, const float* m1, const float* v1,
                        const float* g2, const float* b2, const float* m2, const float* v2,
                        float* binv1, float* bbeta1, float* binv2, float* bbeta2) {
    int c = threadIdx.x;
    float i1 = g1[c] * rsqrtf(v1[c] + EPS);
    binv1[c] = i1; bbeta1[c] = b1[c] - m1[c] * i1;
    float i2 = g2[c] * rsqrtf(v2[c] + EPS);
    binv2[c] = i2; bbeta2[c] = b2[c] - m2[c] * i2;
}

__device__ __forceinline__ void gl_lds16(const __bf16* g, __bf16* l) {
    __builtin_amdgcn_global_load_lds(
        (const __attribute__((address_space(1))) void*)g,
        (__attribute__((address_space(3))) void*)l, 16, 0, 0);
}

template <bool C1>
__global__ __launch_bounds__(256, 2)
void conv_kern(const __bf16* __restrict__ src,   // xm (conv1) or u (conv2), NHWC bf16
               const __bf16* __restrict__ wp,    // packed weights
               const float* __restrict__ maskg,  // mask [B,HW]
               const float* __restrict__ vec,    // vector [B,C] (conv1 only)
               const float* __restrict__ binv, const float* __restrict__ bbeta,
               const float* __restrict__ xin,    // identity x NCHW f32 (conv2 only)
               void* __restrict__ dstv) {
    __shared__ __align__(16) __bf16 s_in[2 * 6 * 66 * 8];    // 12672 B
    __shared__ __align__(16) __bf16 s_w[9 * 2 * 128 * 8];    // 36864 B

    const int tid = threadIdx.x;
    const int lane = tid & 63, wave = tid >> 6;
    const int xlane = lane & 31, halfid = lane >> 5;
    const int band = blockIdx.x, coblk = blockIdx.y, img = blockIdx.z;
    const int y0 = band * 4;
    const int co0c = coblk * 128;
    const int pxw = C1 ? (wave >> 1) : (wave & 1);   // pixel-half of wave
    const int cow = C1 ? (wave & 1) : (wave >> 1);   // co-half of wave

    f32x16 acc[4][2];
    #pragma unroll
    for (int a = 0; a < 4; ++a)
        #pragma unroll
        for (int b = 0; b < 2; ++b)
            #pragma unroll
            for (int r = 0; r < 16; ++r) acc[a][b][r] = 0.f;

    const __bf16* wblk = wp + (size_t)coblk * (16 * 9 * 2 * 128 * 8);
    const float* maskp = maskg + (size_t)img * HW;

    for (int chunk = 0; chunk < 16; ++chunk) {
        __syncthreads();
        // ---- stage input tile: rows y0-1..y0+4, cols -1..64, ci chunk*16..+15 ----
        for (int e = tid; e < 792; e += 256) {
            int half = e & 1, r = e >> 1;            // r in [0,396)
            int yy = r / 66, xx = r - yy * 66;
            int gy = y0 - 1 + yy, gx = xx - 1;
            bf16x8 v = {};
            if ((unsigned)gy < 56u && (unsigned)gx < 56u)
                v = *(const bf16x8*)&src[((size_t)(img * Hh + gy) * Ww + gx) * Cc +
                                          chunk * 16 + half * 8];
            *(bf16x8*)&s_in[((half * 6 + yy) * 66 + xx) * 8] = v;
        }
        // ---- stage weights (contiguous 36864 B) via global_load_lds width 16 ----
        {
            const __bf16* g = wblk + (size_t)chunk * (9 * 2 * 128 * 8);
            #pragma unroll
            for (int i = 0; i < 9; ++i) {
                int unit = wave * 576 + i * 64;      // wave-uniform 16B-unit offset
                gl_lds16(g + (size_t)(unit + lane) * 8, &s_w[unit * 8]);
            }
        }
        asm volatile("s_waitcnt vmcnt(0)" ::: "memory");
        __syncthreads();

        // ---- 9 taps x 8 mfma ----
        #pragma unroll
        for (int kh = 0; kh < 3; ++kh)
            #pragma unroll
            for (int kw = 0; kw < 3; ++kw) {
                const int tap = kh * 3 + kw;
                bf16x8 wf[2], inf[4];
                #pragma unroll
                for (int jt = 0; jt < 2; ++jt)
                    wf[jt] = *(const bf16x8*)&s_w[((tap * 2 + halfid) * 128 +
                                                   (cow * 2 + jt) * 32 + xlane) * 8];
                #pragma unroll
                for (int it = 0; it < 4; ++it) {
                    int tg = pxw * 4 + it;
                    int yy = (tg >> 1) + kh;
                    int xx = (tg & 1) * 32 + xlane + kw;
                    inf[it] = *(const bf16x8*)&s_in[((halfid * 6 + yy) * 66 + xx) * 8];
                }
                #pragma unroll
                for (int it = 0; it < 4; ++it)
                    #pragma unroll
                    for (int jt = 0; jt < 2; ++jt) {
                        if constexpr (C1)
                            acc[it][jt] = __builtin_amdgcn_mfma_f32_32x32x16_bf16(
                                inf[it], wf[jt], acc[it][jt], 0, 0, 0);
                        else
                            acc[it][jt] = __builtin_amdgcn_mfma_f32_32x32x16_bf16(
                                wf[jt], inf[it], acc[it][jt], 0, 0, 0);
                    }
            }
    }

    // ---- epilogue ----
    if constexpr (C1) {
        // D: row = pixel, col(lane&31) = co. Store u NHWC bf16.
        __bf16* u = (__bf16*)dstv;
        float iv[2], bt[2], vv[2]; int cog[2];
        #pragma unroll
        for (int jt = 0; jt < 2; ++jt) {
            cog[jt] = co0c + (cow * 2 + jt) * 32 + xlane;
            iv[jt] = binv[cog[jt]];
            bt[jt] = bbeta[cog[jt]];
            vv[jt] = vec[img * Cc + cog[jt]];
        }
        #pragma unroll
        for (int it = 0; it < 4; ++it) {
            int tg = pxw * 4 + it;
            int y = y0 + (tg >> 1), xb = (tg & 1) * 32;
            #pragma unroll
            for (int reg = 0; reg < 16; ++reg) {
                int x = xb + (reg & 3) + 8 * (reg >> 2) + 4 * halfid;
                if (x < 56) {
                    float mv = maskp[y * 56 + x];
                    size_t base = ((size_t)(img * Hh + y) * Ww + x) * Cc;
                    #pragma unroll
                    for (int jt = 0; jt < 2; ++jt) {
                        float o = fmaxf(fmaf(acc[it][jt][reg], iv[jt], bt[jt]), 0.f)
                                  * mv * vv[jt];
                        u[base + cog[jt]] = (__bf16)o;
                    }
                }
            }
        }
    } else {
        // D: row = co, col(lane&31) = pixel. Store out NCHW f32 with identity+relu.
        float* outp = (float*)dstv;
        int ya[4], xa[4]; float mva[4]; bool ok[4];
        #pragma unroll
        for (int it = 0; it < 4; ++it) {
            int tg = pxw * 4 + it;
            ya[it] = y0 + (tg >> 1);
            xa[it] = (tg & 1) * 32 + xlane;
            ok[it] = xa[it] < 56;
            mva[it] = ok[it] ? maskp[ya[it] * 56 + xa[it]] : 0.f;
        }
        #pragma unroll
        for (int jt = 0; jt < 2; ++jt) {
            int cb = co0c + (cow * 2 + jt) * 32;
            #pragma unroll
            for (int rg = 0; rg < 4; ++rg) {
                int c4 = cb + 8 * rg + 4 * halfid;
                float4 iv4 = *(const float4*)&binv[c4];
                float4 bt4 = *(const float4*)&bbeta[c4];
                float ivv[4] = {iv4.x, iv4.y, iv4.z, iv4.w};
                float btv[4] = {bt4.x, bt4.y, bt4.z, bt4.w};
                #pragma unroll
                for (int j = 0; j < 4; ++j) {
                    int reg = rg * 4 + j;
                    int co = c4 + j;
                    size_t cbase = (size_t)(img * Cc + co) * HW;
                    #pragma unroll
                    for (int it = 0; it < 4; ++it) {
                        if (ok[it]) {
                            size_t oa = cbase + ya[it] * 56 + xa[it];
                            float o = fmaxf(
                                xin[oa] + mva[it] * fmaf(acc[it][jt][reg], ivv[j], btv[j]),
                                0.f);
                            outp[oa] = o;
                        }
                    }
                }
            }
        }
    }
}

extern "C" void kernel_launch(void* const* d_in, const int* in_sizes, int n_in,
                              void* d_out, int out_size, void* d_ws, size_t ws_size,
                              hipStream_t stream) {
    const float* x    = (const float*)d_in[0];
    const float* mask = (const float*)d_in[1];
    const float* md   = (const float*)d_in[2];
    const float* vec  = (const float*)d_in[3];
    const float* w1   = (const float*)d_in[4];
    const float* bn1g = (const float*)d_in[5];
    const float* bn1b = (const float*)d_in[6];
    const float* bn1m = (const float*)d_in[7];
    const float* bn1v = (const float*)d_in[8];
    const float* w2   = (const float*)d_in[9];
    const float* bn2g = (const float*)d_in[10];
    const float* bn2b = (const float*)d_in[11];
    const float* bn2m = (const float*)d_in[12];
    const float* bn2v = (const float*)d_in[13];
    float* out = (float*)d_out;

    const size_t nhwc = (size_t)Bn * HW * Cc;     // 25,690,112
    __bf16* xm  = (__bf16*)d_ws;
    __bf16* u   = xm + nhwc;
    __bf16* wp1 = u + nhwc;
    __bf16* wp2 = wp1 + WP_ELEMS;
    float* binv1  = (float*)(wp2 + WP_ELEMS);
    float* bbeta1 = binv1 + 256;
    float* binv2  = bbeta1 + 256;
    float* bbeta2 = binv2 + 256;

    pack_xm<<<dim3(Bn * HW / 32), dim3(256), 0, stream>>>(x, md, xm);
    pack_w<<<dim3(WP_ELEMS / 256, 2), dim3(256), 0, stream>>>(w1, w2, wp1, wp2);
    bn_prep<<<dim3(1), dim3(256), 0, stream>>>(bn1g, bn1b, bn1m, bn1v,
                                               bn2g, bn2b, bn2m, bn2v,
                                               binv1, bbeta1, binv2, bbeta2);

    dim3 grid(14, 2, Bn);
    conv_kern<true><<<grid, dim3(256), 0, stream>>>(
        xm, wp1, mask, vec, binv1, bbeta1, nullptr, u);
    conv_kern<false><<<grid, dim3(256), 0, stream>>>(
        u, wp2, mask, nullptr, binv2, bbeta2, x, out);
}